// Round 3
// baseline (123.219 us; speedup 1.0000x reference)
//
#include <hip/hip_runtime.h>
#include <hip/hip_bf16.h>

#define BATCH 4
#define CHAN 128
#define HGT 96
#define WID 160
#define HW (HGT * WID)
#define THREADS 256
#define TENSOR_ELEMS (BATCH * CHAN * HGT * WID)
#define WS_NEED ((size_t)TENSOR_ELEMS * 2)   // tgt NHWC bf16 only

typedef __attribute__((ext_vector_type(8))) short short8;
typedef __attribute__((ext_vector_type(4))) float float4v;

// Output channel index for displacement (dy,dx), matching _displacements(4) order.
__device__ __forceinline__ int chan_of(int dy, int dx) {
    if (dy == 0 && dx == 0) return 0;
    if (dx == 0) { int i = dy < 0 ? -dy : dy; return 1 + (i - 1) * 20 + (dy < 0 ? 0 : 1); }
    if (dy == 0) { int i = dx < 0 ? -dx : dx; return 1 + (i - 1) * 20 + (dx < 0 ? 2 : 3); }
    int i = dy < 0 ? -dy : dy;
    int j = dx < 0 ? -dx : dx;
    int s = (dy < 0) ? (dx < 0 ? 0 : 2) : (dx < 0 ? 3 : 1);
    return 1 + (i - 1) * 20 + 4 + (j - 1) * 4 + s;
}

// Packed fp32x2 -> bf16x2 (v_cvt_pk_bf16_f32).
__device__ __forceinline__ unsigned pk2(float a, float b) {
    __hip_bfloat162 h = __float22bfloat162_rn(make_float2(a, b));
    unsigned u;
    __builtin_memcpy(&u, &h, 4);
    return u;
}

union sl_u { uint4 v; short8 s; };

// ---------------------------------------------------------------------------
// Pre-pass: tgt NCHW f32 -> NHWC bf16 (src stays NCHW; its A-loads overlap the
// main kernel's DMA drain, so converting it would be pure extra traffic).
// ---------------------------------------------------------------------------
__global__ __launch_bounds__(THREADS)
void nhwc_bf16_tgt(const float* __restrict__ tgt, ushort* __restrict__ ws) {
    __shared__ unsigned s_t[64][65];
    int r = blockIdx.x;                 // 3 * 96 * 4 = 1152
    const int xb = r % 3; r /= 3;
    const int y  = r % HGT; r /= HGT;
    const int b  = r;                   // 0..3
    const int x0 = xb * 64;
    const int npx = (x0 + 64 <= WID) ? 64 : (WID - x0);   // 64 or 32

    const int t  = threadIdx.x;
    const int x1 = t & 63, cp0 = t >> 6;
    if (x1 < npx) {
        const int base = (b * CHAN * HGT + y) * WID + x0 + x1;  // channel 0
        #pragma unroll
        for (int i = 0; i < 16; ++i) {
            const int cp = cp0 + i * 4;                 // channel pair 0..63
            s_t[cp][x1] = pk2(tgt[base + (2 * cp) * HW],
                              tgt[base + (2 * cp + 1) * HW]);
        }
    }
    __syncthreads();
    const int x2 = t >> 2, g = t & 3;
    if (x2 < npx) {
        ushort* op = ws + ((size_t)(b * HGT + y) * WID + x0 + x2) * CHAN + g * 32;
        #pragma unroll
        for (int k = 0; k < 4; ++k) {
            uint4 v;
            v.x = s_t[g * 16 + k * 4 + 0][x2];
            v.y = s_t[g * 16 + k * 4 + 1][x2];
            v.z = s_t[g * 16 + k * 4 + 2][x2];
            v.w = s_t[g * 16 + k * 4 + 3][x2];
            *(uint4*)(op + k * 8) = v;
        }
    }
}

// ---------------------------------------------------------------------------
// Main kernel: B via global_load_lds DMA from NHWC bf16 (XOR swizzle on the
// GLOBAL source octet, linear LDS dest); A via NCHW f32 scalar loads (4-line
// coalescing, issued before the DMA so cvt overlaps the DMA flight).
// Epilogue: accumulators -> LDS [27][68] f32 tile -> float4 stores with lanes
// spanning x inside ONE channel plane (~30 L2 line-requests/wave vs ~650 for
// the old per-lane channel-scattered scalar stores — the R2 bottleneck).
// ---------------------------------------------------------------------------
__global__ __launch_bounds__(THREADS, 4)
void cost_volume_mfma(const float* __restrict__ src,
                      const ushort* __restrict__ tgtT,
                      float* __restrict__ out) {
    __shared__ __align__(16) uint4 s_b[2432];   // 38912 B -> 4 blocks/CU
    __shared__ int s_tab[27];                   // cix -> oc*HW

    const int tid  = threadIdx.x;
    const int wv   = tid >> 6;
    const int lane = tid & 63;
    const int q    = lane >> 4;
    const int ln   = lane & 15;

    // XCD-affinity swizzle: blockIdx%8 -> (batch, y-half) slab.
    const int w    = blockIdx.x;      // 0..2879
    const int slab = w & 7;
    const int b    = slab >> 1;
    const int yh   = slab & 1;
    const int r0   = w >> 3;
    const int dyg  = r0 % 3;
    const int t    = r0 / 3;
    const int x0   = (t % 10) * 16;
    const int y0   = yh * 48 + (t / 10) * 4;
    const int dy0  = dyg * 3 - 4;

    if (tid < 27) s_tab[tid] = chan_of(dy0 + tid / 9, tid % 9 - 4) * HW;

    // ---- A payload first (oldest in vmcnt queue -> cvt waits only on these)
    const int y = y0 + wv;
    const int sbase = (b * CHAN * HGT + y) * WID + x0 + ln + q * 8 * HW;
    float apay[32];
    #pragma unroll
    for (int ks = 0; ks < 4; ++ks)
        #pragma unroll
        for (int j = 0; j < 8; ++j)
            apay[ks * 8 + j] = src[sbase + (ks * 32 + j) * HW];

    // ---- stage B: 2304 slots, 9 DMA/thread; slot u=(row*24+x)*16+j holds
    // octet j^(x&15); read for octet o fetches slot o^(x&15).
    const ushort* tbase = tgtT + (size_t)b * HGT * WID * CHAN;
    #pragma unroll
    for (int k = 0; k < 9; ++k) {
        const int u   = k * THREADS + tid;
        const int j   = u & 15;
        const int v16 = u >> 4;              // row*24 + x
        const int row = v16 / 24;
        const int x   = v16 - row * 24;
        const int gr  = y0 + dy0 + row;
        const int gx  = x0 - 4 + x;
        const int oct = j ^ (x & 15);
        unsigned* lp = (unsigned*)&s_b[k * THREADS + (tid & ~63)];  // wave base
        if (((unsigned)gr < (unsigned)HGT) && ((unsigned)gx < (unsigned)WID)) {
            const unsigned* gp =
                (const unsigned*)(tbase + ((gr * WID + gx) * CHAN + oct * 8));
            __builtin_amdgcn_global_load_lds(gp, lp, 16, 0, 0);
        } else {
            s_b[u] = make_uint4(0u, 0u, 0u, 0u);   // disjoint from DMA targets
        }
    }

    // ---- convert A (overlaps DMA flight) ----
    short8 afr[4];
    #pragma unroll
    for (int ks = 0; ks < 4; ++ks) {
        sl_u f;
        f.v.x = pk2(apay[ks * 8 + 0], apay[ks * 8 + 1]);
        f.v.y = pk2(apay[ks * 8 + 2], apay[ks * 8 + 3]);
        f.v.z = pk2(apay[ks * 8 + 4], apay[ks * 8 + 5]);
        f.v.w = pk2(apay[ks * 8 + 6], apay[ks * 8 + 7]);
        afr[ks] = f.s;
    }

    __syncthreads();   // drains DMA (vmcnt) + zero-fill (lgkmcnt)

    // ---- compute: 24 ds_read_b128 + 24 MFMA per wave, accs held in regs ----
    float4v aa0[3], aa1[3];
    #pragma unroll
    for (int dyi = 0; dyi < 3; ++dyi) {
        const int rr = wv + dyi;
        float4v a0 = (float4v){0.f, 0.f, 0.f, 0.f};
        float4v a1 = (float4v){0.f, 0.f, 0.f, 0.f};
        #pragma unroll
        for (int ks = 0; ks < 4; ++ks) {
            sl_u b0;   // nt=0: x = ln
            b0.v = s_b[(rr * 24 + ln) * 16 + ((q + ks * 4) ^ ln)];
            a0 = __builtin_amdgcn_mfma_f32_16x16x32_bf16(afr[ks], b0.s, a0, 0, 0, 0);
        }
        #pragma unroll
        for (int ks = 0; ks < 4; ++ks) {
            sl_u b1;   // nt=1: x = 16+ln
            b1.v = s_b[(rr * 24 + 16 + ln) * 16 + ((q + ks * 4) ^ ln)];
            a1 = __builtin_amdgcn_mfma_f32_16x16x32_bf16(afr[ks], b1.s, a1, 0, 0, 0);
        }
        aa0[dyi] = a0;
        aa1[dyi] = a1;
    }

    __syncthreads();   // all s_b reads done -> safe to overlay s_o

    // ---- banded accs -> LDS [27 ch][68] f32 (pad 68: write side = consecutive
    // cix per 9-lane group -> bank stride 4, one 2-way alias = free; 16B-aligned
    // rows for float4 readback) ----
    float* s_o = (float*)s_b;
    const float inv = 1.0f / 81.0f;
    #pragma unroll
    for (int dyi = 0; dyi < 3; ++dyi) {
        #pragma unroll
        for (int reg = 0; reg < 4; ++reg) {
            const int m = q * 4 + reg;
            const int t0x = ln - m;           // dx+4 for nt=0
            if ((unsigned)t0x <= 8u)
                s_o[(dyi * 9 + t0x) * 68 + wv * 16 + m] = aa0[dyi][reg] * inv;
            const int t1x = ln + 16 - m;      // dx+4 for nt=1
            if ((unsigned)t1x <= 8u)
                s_o[(dyi * 9 + t1x) * 68 + wv * 16 + m] = aa1[dyi][reg] * inv;
        }
    }
    __syncthreads();

    // ---- store: 432 float4 tasks; lanes span x within one (ch,y) row ----
    const size_t ob = (size_t)b * 81 * HW + (size_t)y0 * WID + x0;
    #pragma unroll
    for (int it = 0; it < 2; ++it) {
        const int v = it * THREADS + tid;
        if (v < 432) {
            const int xq  = v & 3;
            const int row = v >> 2;           // 0..107 = cix*4 + yy
            const int cix = row >> 2;
            const int yy  = row & 3;
            float4v val = *(const float4v*)&s_o[cix * 68 + yy * 16 + xq * 4];
            *(float4v*)&out[ob + s_tab[cix] + yy * WID + xq * 4] = val;
        }
    }
}

// ---------------------------------------------------------------------------
// Fallback (ws too small): R1 single-kernel path, correctness-safe.
// ---------------------------------------------------------------------------
#define ST_DECODE(TAG, U)                                                     \
    const int oct##TAG = (U) & 15;                                            \
    const int u4##TAG  = (U) >> 4;                                            \
    const int row##TAG = (u4##TAG * 43) >> 8;                                 \
    const int xq##TAG  = u4##TAG - row##TAG * 6;                              \
    const int gr##TAG  = y0 + dy0 + row##TAG;                                 \
    const int gx##TAG  = x0 - 4 + xq##TAG * 4;                                \
    const bool ok##TAG = ((unsigned)gr##TAG < (unsigned)HGT) &&               \
                         ((unsigned)gx##TAG < (unsigned)WID);                 \
    const int ga##TAG  = tb + (oct##TAG * 8 * HGT + gr##TAG) * WID + gx##TAG;

#define ST_ISSUE(TAG, COND)                                                   \
    _Pragma("unroll")                                                         \
    for (int j = 0; j < 8; ++j)                                               \
        p##TAG[j] = (COND) ? *(const float4v*)(tgt + ga##TAG + j * HW)        \
                           : (float4v){0.f, 0.f, 0.f, 0.f};

#define ST_WRITE(TAG)                                                         \
    _Pragma("unroll")                                                         \
    for (int i = 0; i < 4; ++i) {                                             \
        const int xl = xq##TAG * 4 + i;                                       \
        uint4 val;                                                            \
        val.x = pk2(p##TAG[0][i], p##TAG[1][i]);                              \
        val.y = pk2(p##TAG[2][i], p##TAG[3][i]);                              \
        val.z = pk2(p##TAG[4][i], p##TAG[5][i]);                              \
        val.w = pk2(p##TAG[6][i], p##TAG[7][i]);                              \
        s_b[(row##TAG * 24 + xl) * 16 + (oct##TAG ^ (xl & 15))] = val;        \
    }

__global__ __launch_bounds__(THREADS, 4)
void cost_volume_fallback(const float* __restrict__ src,
                          const float* __restrict__ tgt,
                          float* __restrict__ out) {
    __shared__ __align__(16) uint4 s_b[2432];
    __shared__ int s_tab[27];

    const int tid  = threadIdx.x;
    const int wv   = tid >> 6;
    const int lane = tid & 63;
    const int q    = lane >> 4;
    const int ln   = lane & 15;

    const int w    = blockIdx.x;
    const int slab = w & 7;
    const int b    = slab >> 1;
    const int yh   = slab & 1;
    const int r0   = w >> 3;
    const int dyg  = r0 % 3;
    const int t    = r0 / 3;
    const int x0   = (t % 10) * 16;
    const int y0   = yh * 48 + (t / 10) * 4;
    const int dy0  = dyg * 3 - 4;

    if (tid < 27) s_tab[tid] = chan_of(dy0 + tid / 9, tid % 9 - 4) * HW;

    const int tb = b * CHAN * HGT * WID;

    ST_DECODE(0, tid)
    ST_DECODE(1, tid + 256)
    ST_DECODE(2, tid + 512)
    const bool has2 = tid < 64;

    float4v p0[8], p1[8], p2[8];
    ST_ISSUE(0, ok0)

    const int y  = y0 + wv;
    const int sbase = (b * CHAN * HGT + y) * WID + x0 + ln + q * 8 * HW;
    float apay[32];
    #pragma unroll
    for (int ks = 0; ks < 4; ++ks)
        #pragma unroll
        for (int j = 0; j < 8; ++j)
            apay[ks * 8 + j] = src[sbase + (ks * 32 + j) * HW];

    ST_ISSUE(1, ok1)
    ST_WRITE(0)
    ST_ISSUE(2, has2 && ok2)
    short8 afr[4];
    #pragma unroll
    for (int ks = 0; ks < 4; ++ks) {
        sl_u f;
        f.v.x = pk2(apay[ks * 8 + 0], apay[ks * 8 + 1]);
        f.v.y = pk2(apay[ks * 8 + 2], apay[ks * 8 + 3]);
        f.v.z = pk2(apay[ks * 8 + 4], apay[ks * 8 + 5]);
        f.v.w = pk2(apay[ks * 8 + 6], apay[ks * 8 + 7]);
        afr[ks] = f.s;
    }
    ST_WRITE(1)
    if (has2) { ST_WRITE(2) }

    __syncthreads();

    const float inv = 1.0f / 81.0f;
    const int obase = (b * 81 * HGT + y) * WID + x0;
    #pragma unroll
    for (int dyi = 0; dyi < 3; ++dyi) {
        const int rr = wv + dyi;
        float4v a0 = (float4v){0.f, 0.f, 0.f, 0.f};
        float4v a1 = (float4v){0.f, 0.f, 0.f, 0.f};
        #pragma unroll
        for (int ks = 0; ks < 4; ++ks) {
            sl_u b0;
            b0.v = s_b[(rr * 24 + ln) * 16 + ((q + ks * 4) ^ ln)];
            a0 = __builtin_amdgcn_mfma_f32_16x16x32_bf16(afr[ks], b0.s, a0, 0, 0, 0);
        }
        #pragma unroll
        for (int ks = 0; ks < 4; ++ks) {
            sl_u b1;
            b1.v = s_b[(rr * 24 + 16 + ln) * 16 + ((q + ks * 4) ^ ln)];
            a1 = __builtin_amdgcn_mfma_f32_16x16x32_bf16(afr[ks], b1.s, a1, 0, 0, 0);
        }
        #pragma unroll
        for (int reg = 0; reg < 4; ++reg) {
            const int m = q * 4 + reg;
            const int t0x = ln - m;
            if ((unsigned)t0x <= 8u)
                out[obase + s_tab[dyi * 9 + t0x] + m] = a0[reg] * inv;
            const int t1x = ln + 16 - m;
            if ((unsigned)t1x <= 8u)
                out[obase + s_tab[dyi * 9 + t1x] + m] = a1[reg] * inv;
        }
    }
}

extern "C" void kernel_launch(void* const* d_in, const int* in_sizes, int n_in,
                              void* d_out, int out_size, void* d_ws, size_t ws_size,
                              hipStream_t stream) {
    const float* src = (const float*)d_in[0];
    const float* tgt = (const float*)d_in[1];
    float* out = (float*)d_out;
    if (d_ws && ws_size >= WS_NEED) {
        ushort* ws = (ushort*)d_ws;
        nhwc_bf16_tgt<<<dim3(1152, 1, 1), dim3(THREADS, 1, 1), 0, stream>>>(tgt, ws);
        cost_volume_mfma<<<dim3(2880, 1, 1), dim3(THREADS, 1, 1), 0, stream>>>(src, ws, out);
    } else {
        cost_volume_fallback<<<dim3(2880, 1, 1), dim3(THREADS, 1, 1), 0, stream>>>(src, tgt, out);
    }
}

// Round 4
// 117.329 us; speedup vs baseline: 1.0502x; 1.0502x over previous
//
#include <hip/hip_runtime.h>
#include <hip/hip_bf16.h>

#define BATCH 4
#define CHAN 128
#define HGT 96
#define WID 160
#define HW (HGT * WID)
#define THREADS 256
#define TENSOR_ELEMS (BATCH * CHAN * HGT * WID)
#define WS_NEED ((size_t)TENSOR_ELEMS * 2)   // tgt NHWC bf16 only

typedef __attribute__((ext_vector_type(8))) short short8;
typedef __attribute__((ext_vector_type(4))) float float4v;

// Output channel index for displacement (dy,dx), matching _displacements(4) order.
__device__ __forceinline__ int chan_of(int dy, int dx) {
    if (dy == 0 && dx == 0) return 0;
    if (dx == 0) { int i = dy < 0 ? -dy : dy; return 1 + (i - 1) * 20 + (dy < 0 ? 0 : 1); }
    if (dy == 0) { int i = dx < 0 ? -dx : dx; return 1 + (i - 1) * 20 + (dx < 0 ? 2 : 3); }
    int i = dy < 0 ? -dy : dy;
    int j = dx < 0 ? -dx : dx;
    int s = (dy < 0) ? (dx < 0 ? 0 : 2) : (dx < 0 ? 3 : 1);
    return 1 + (i - 1) * 20 + 4 + (j - 1) * 4 + s;
}

// Packed fp32x2 -> bf16x2 (v_cvt_pk_bf16_f32).
__device__ __forceinline__ unsigned pk2(float a, float b) {
    __hip_bfloat162 h = __float22bfloat162_rn(make_float2(a, b));
    unsigned u;
    __builtin_memcpy(&u, &h, 4);
    return u;
}

union sl_u { uint4 v; short8 s; };

// ---------------------------------------------------------------------------
// Pre-pass: tgt NCHW f32 -> NHWC bf16 (unchanged, R3-verified).
// ---------------------------------------------------------------------------
__global__ __launch_bounds__(THREADS)
void nhwc_bf16_tgt(const float* __restrict__ tgt, ushort* __restrict__ ws) {
    __shared__ unsigned s_t[64][65];
    int r = blockIdx.x;                 // 3 * 96 * 4 = 1152
    const int xb = r % 3; r /= 3;
    const int y  = r % HGT; r /= HGT;
    const int b  = r;                   // 0..3
    const int x0 = xb * 64;
    const int npx = (x0 + 64 <= WID) ? 64 : (WID - x0);   // 64 or 32

    const int t  = threadIdx.x;
    const int x1 = t & 63, cp0 = t >> 6;
    if (x1 < npx) {
        const int base = (b * CHAN * HGT + y) * WID + x0 + x1;  // channel 0
        #pragma unroll
        for (int i = 0; i < 16; ++i) {
            const int cp = cp0 + i * 4;                 // channel pair 0..63
            s_t[cp][x1] = pk2(tgt[base + (2 * cp) * HW],
                              tgt[base + (2 * cp + 1) * HW]);
        }
    }
    __syncthreads();
    const int x2 = t >> 2, g = t & 3;
    if (x2 < npx) {
        ushort* op = ws + ((size_t)(b * HGT + y) * WID + x0 + x2) * CHAN + g * 32;
        #pragma unroll
        for (int k = 0; k < 4; ++k) {
            uint4 v;
            v.x = s_t[g * 16 + k * 4 + 0][x2];
            v.y = s_t[g * 16 + k * 4 + 1][x2];
            v.z = s_t[g * 16 + k * 4 + 2][x2];
            v.w = s_t[g * 16 + k * 4 + 3][x2];
            *(uint4*)(op + k * 8) = v;
        }
    }
}

// ---------------------------------------------------------------------------
// Main kernel v4: ONE block per (b, y-quad, x-tile) computes ALL 81
// displacements (merges the former 3 dy-group blocks: 1x A traffic instead of
// 3x, 0.67x B traffic, 1/3 the setup/barrier/epilogue overhead, same MFMA
// work). B window = 12 rows x 24 x x 128 c bf16 via global_load_lds DMA with
// the verified XOR-octet source swizzle; 75.8 KB LDS -> 2 blocks/CU.
// ---------------------------------------------------------------------------
__global__ __launch_bounds__(THREADS, 2)
void cost_volume_mfma(const float* __restrict__ src,
                      const ushort* __restrict__ tgtT,
                      float* __restrict__ out) {
    // 12*24*16 = 4608 DMA slots + 128 pad slots so nt=1 reads at x up to 31
    // (band-masked-off, matching R3's proven pattern) stay in-bounds.
    __shared__ __align__(16) uint4 s_b[4736];   // 75776 B
    __shared__ int s_tab[81];                   // cix -> oc*HW

    const int tid  = threadIdx.x;
    const int wv   = tid >> 6;
    const int lane = tid & 63;
    const int q    = lane >> 4;
    const int ln   = lane & 15;

    // XCD-affinity swizzle: blockIdx%8 -> (batch, y-half) slab.
    const int w    = blockIdx.x;      // 0..959
    const int slab = w & 7;
    const int b    = slab >> 1;
    const int yh   = slab & 1;
    const int t    = w >> 3;          // 0..119
    const int x0   = (t % 10) * 16;
    const int y0   = yh * 48 + (t / 10) * 4;

    if (tid < 81) s_tab[tid] = chan_of(tid / 9 - 4, tid % 9 - 4) * HW;

    // ---- A payload first (oldest in vmcnt queue -> cvt waits only on these)
    const int y = y0 + wv;
    const int sbase = (b * CHAN * HGT + y) * WID + x0 + ln + q * 8 * HW;
    float apay[32];
    #pragma unroll
    for (int ks = 0; ks < 4; ++ks)
        #pragma unroll
        for (int j = 0; j < 8; ++j)
            apay[ks * 8 + j] = src[sbase + (ks * 32 + j) * HW];

    // ---- stage B: 4608 slots, 18 DMA/thread; slot u=(row*24+x)*16+j holds
    // octet j^(x&15); read for octet o fetches slot o^(x&15).
    const ushort* tbase = tgtT + (size_t)b * HGT * WID * CHAN;
    #pragma unroll
    for (int k = 0; k < 18; ++k) {
        const int u   = k * THREADS + tid;
        const int j   = u & 15;
        const int v16 = u >> 4;              // row*24 + x, 0..287
        const int row = v16 / 24;
        const int x   = v16 - row * 24;
        const int gr  = y0 - 4 + row;        // rows y0-4 .. y0+7
        const int gx  = x0 - 4 + x;
        const int oct = j ^ (x & 15);
        unsigned* lp = (unsigned*)&s_b[k * THREADS + (tid & ~63)];  // wave base
        if (((unsigned)gr < (unsigned)HGT) && ((unsigned)gx < (unsigned)WID)) {
            const unsigned* gp =
                (const unsigned*)(tbase + ((gr * WID + gx) * CHAN + oct * 8));
            __builtin_amdgcn_global_load_lds(gp, lp, 16, 0, 0);
        } else {
            s_b[u] = make_uint4(0u, 0u, 0u, 0u);   // disjoint from DMA targets
        }
    }

    // ---- convert A (overlaps DMA flight) ----
    short8 afr[4];
    #pragma unroll
    for (int ks = 0; ks < 4; ++ks) {
        sl_u f;
        f.v.x = pk2(apay[ks * 8 + 0], apay[ks * 8 + 1]);
        f.v.y = pk2(apay[ks * 8 + 2], apay[ks * 8 + 3]);
        f.v.z = pk2(apay[ks * 8 + 4], apay[ks * 8 + 5]);
        f.v.w = pk2(apay[ks * 8 + 6], apay[ks * 8 + 7]);
        afr[ks] = f.s;
    }

    __syncthreads();   // drains DMA (vmcnt) + zero-fill (lgkmcnt)

    // ---- compute: 9 dys x (8 ds_read_b128 + 8 MFMA) per wave ----
    float4v aa0[9], aa1[9];
    #pragma unroll
    for (int dyi = 0; dyi < 9; ++dyi) {
        const int rr = wv + dyi;              // LDS row = (y+dy) - (y0-4)
        float4v a0 = (float4v){0.f, 0.f, 0.f, 0.f};
        float4v a1 = (float4v){0.f, 0.f, 0.f, 0.f};
        #pragma unroll
        for (int ks = 0; ks < 4; ++ks) {
            sl_u b0;   // nt=0: x = ln
            b0.v = s_b[(rr * 24 + ln) * 16 + ((q + ks * 4) ^ ln)];
            a0 = __builtin_amdgcn_mfma_f32_16x16x32_bf16(afr[ks], b0.s, a0, 0, 0, 0);
        }
        #pragma unroll
        for (int ks = 0; ks < 4; ++ks) {
            sl_u b1;   // nt=1: x = 16+ln
            b1.v = s_b[(rr * 24 + 16 + ln) * 16 + ((q + ks * 4) ^ ln)];
            a1 = __builtin_amdgcn_mfma_f32_16x16x32_bf16(afr[ks], b1.s, a1, 0, 0, 0);
        }
        aa0[dyi] = a0;
        aa1[dyi] = a1;
    }

    __syncthreads();   // all s_b reads done -> safe to overlay s_o

    // ---- banded accs -> LDS [81 ch][68] f32 ----
    float* s_o = (float*)s_b;
    const float inv = 1.0f / 81.0f;
    #pragma unroll
    for (int dyi = 0; dyi < 9; ++dyi) {
        #pragma unroll
        for (int reg = 0; reg < 4; ++reg) {
            const int m = q * 4 + reg;
            const int t0x = ln - m;           // dx+4 for nt=0
            if ((unsigned)t0x <= 8u)
                s_o[(dyi * 9 + t0x) * 68 + wv * 16 + m] = aa0[dyi][reg] * inv;
            const int t1x = ln + 16 - m;      // dx+4 for nt=1
            if ((unsigned)t1x <= 8u)
                s_o[(dyi * 9 + t1x) * 68 + wv * 16 + m] = aa1[dyi][reg] * inv;
        }
    }
    __syncthreads();

    // ---- store: 1296 float4 tasks; lanes span x within one (ch,y) row ----
    const size_t ob = (size_t)b * 81 * HW + (size_t)y0 * WID + x0;
    #pragma unroll
    for (int it = 0; it < 6; ++it) {
        const int v = it * THREADS + tid;
        if (v < 1296) {
            const int xq  = v & 3;
            const int row = v >> 2;           // 0..323 = cix*4 + yy
            const int cix = row >> 2;
            const int yy  = row & 3;
            float4v val = *(const float4v*)&s_o[cix * 68 + yy * 16 + xq * 4];
            *(float4v*)&out[ob + s_tab[cix] + yy * WID + xq * 4] = val;
        }
    }
}

// ---------------------------------------------------------------------------
// Fallback (ws too small): R1 single-kernel path, correctness-safe.
// ---------------------------------------------------------------------------
#define ST_DECODE(TAG, U)                                                     \
    const int oct##TAG = (U) & 15;                                            \
    const int u4##TAG  = (U) >> 4;                                            \
    const int row##TAG = (u4##TAG * 43) >> 8;                                 \
    const int xq##TAG  = u4##TAG - row##TAG * 6;                              \
    const int gr##TAG  = y0 + dy0 + row##TAG;                                 \
    const int gx##TAG  = x0 - 4 + xq##TAG * 4;                                \
    const bool ok##TAG = ((unsigned)gr##TAG < (unsigned)HGT) &&               \
                         ((unsigned)gx##TAG < (unsigned)WID);                 \
    const int ga##TAG  = tb + (oct##TAG * 8 * HGT + gr##TAG) * WID + gx##TAG;

#define ST_ISSUE(TAG, COND)                                                   \
    _Pragma("unroll")                                                         \
    for (int j = 0; j < 8; ++j)                                               \
        p##TAG[j] = (COND) ? *(const float4v*)(tgt + ga##TAG + j * HW)        \
                           : (float4v){0.f, 0.f, 0.f, 0.f};

#define ST_WRITE(TAG)                                                         \
    _Pragma("unroll")                                                         \
    for (int i = 0; i < 4; ++i) {                                             \
        const int xl = xq##TAG * 4 + i;                                       \
        uint4 val;                                                            \
        val.x = pk2(p##TAG[0][i], p##TAG[1][i]);                              \
        val.y = pk2(p##TAG[2][i], p##TAG[3][i]);                              \
        val.z = pk2(p##TAG[4][i], p##TAG[5][i]);                              \
        val.w = pk2(p##TAG[6][i], p##TAG[7][i]);                              \
        s_b[(row##TAG * 24 + xl) * 16 + (oct##TAG ^ (xl & 15))] = val;        \
    }

__global__ __launch_bounds__(THREADS, 4)
void cost_volume_fallback(const float* __restrict__ src,
                          const float* __restrict__ tgt,
                          float* __restrict__ out) {
    __shared__ __align__(16) uint4 s_b[2432];
    __shared__ int s_tab[27];

    const int tid  = threadIdx.x;
    const int wv   = tid >> 6;
    const int lane = tid & 63;
    const int q    = lane >> 4;
    const int ln   = lane & 15;

    const int w    = blockIdx.x;
    const int slab = w & 7;
    const int b    = slab >> 1;
    const int yh   = slab & 1;
    const int r0   = w >> 3;
    const int dyg  = r0 % 3;
    const int t    = r0 / 3;
    const int x0   = (t % 10) * 16;
    const int y0   = yh * 48 + (t / 10) * 4;
    const int dy0  = dyg * 3 - 4;

    if (tid < 27) s_tab[tid] = chan_of(dy0 + tid / 9, tid % 9 - 4) * HW;

    const int tb = b * CHAN * HGT * WID;

    ST_DECODE(0, tid)
    ST_DECODE(1, tid + 256)
    ST_DECODE(2, tid + 512)
    const bool has2 = tid < 64;

    float4v p0[8], p1[8], p2[8];
    ST_ISSUE(0, ok0)

    const int y  = y0 + wv;
    const int sbase = (b * CHAN * HGT + y) * WID + x0 + ln + q * 8 * HW;
    float apay[32];
    #pragma unroll
    for (int ks = 0; ks < 4; ++ks)
        #pragma unroll
        for (int j = 0; j < 8; ++j)
            apay[ks * 8 + j] = src[sbase + (ks * 32 + j) * HW];

    ST_ISSUE(1, ok1)
    ST_WRITE(0)
    ST_ISSUE(2, has2 && ok2)
    short8 afr[4];
    #pragma unroll
    for (int ks = 0; ks < 4; ++ks) {
        sl_u f;
        f.v.x = pk2(apay[ks * 8 + 0], apay[ks * 8 + 1]);
        f.v.y = pk2(apay[ks * 8 + 2], apay[ks * 8 + 3]);
        f.v.z = pk2(apay[ks * 8 + 4], apay[ks * 8 + 5]);
        f.v.w = pk2(apay[ks * 8 + 6], apay[ks * 8 + 7]);
        afr[ks] = f.s;
    }
    ST_WRITE(1)
    if (has2) { ST_WRITE(2) }

    __syncthreads();

    const float inv = 1.0f / 81.0f;
    const int obase = (b * 81 * HGT + y) * WID + x0;
    #pragma unroll
    for (int dyi = 0; dyi < 3; ++dyi) {
        const int rr = wv + dyi;
        float4v a0 = (float4v){0.f, 0.f, 0.f, 0.f};
        float4v a1 = (float4v){0.f, 0.f, 0.f, 0.f};
        #pragma unroll
        for (int ks = 0; ks < 4; ++ks) {
            sl_u b0;
            b0.v = s_b[(rr * 24 + ln) * 16 + ((q + ks * 4) ^ ln)];
            a0 = __builtin_amdgcn_mfma_f32_16x16x32_bf16(afr[ks], b0.s, a0, 0, 0, 0);
        }
        #pragma unroll
        for (int ks = 0; ks < 4; ++ks) {
            sl_u b1;
            b1.v = s_b[(rr * 24 + 16 + ln) * 16 + ((q + ks * 4) ^ ln)];
            a1 = __builtin_amdgcn_mfma_f32_16x16x32_bf16(afr[ks], b1.s, a1, 0, 0, 0);
        }
        #pragma unroll
        for (int reg = 0; reg < 4; ++reg) {
            const int m = q * 4 + reg;
            const int t0x = ln - m;
            if ((unsigned)t0x <= 8u)
                out[obase + s_tab[dyi * 9 + t0x] + m] = a0[reg] * inv;
            const int t1x = ln + 16 - m;
            if ((unsigned)t1x <= 8u)
                out[obase + s_tab[dyi * 9 + t1x] + m] = a1[reg] * inv;
        }
    }
}

extern "C" void kernel_launch(void* const* d_in, const int* in_sizes, int n_in,
                              void* d_out, int out_size, void* d_ws, size_t ws_size,
                              hipStream_t stream) {
    const float* src = (const float*)d_in[0];
    const float* tgt = (const float*)d_in[1];
    float* out = (float*)d_out;
    if (d_ws && ws_size >= WS_NEED) {
        ushort* ws = (ushort*)d_ws;
        nhwc_bf16_tgt<<<dim3(1152, 1, 1), dim3(THREADS, 1, 1), 0, stream>>>(tgt, ws);
        cost_volume_mfma<<<dim3(960, 1, 1), dim3(THREADS, 1, 1), 0, stream>>>(src, ws, out);
    } else {
        cost_volume_fallback<<<dim3(2880, 1, 1), dim3(THREADS, 1, 1), 0, stream>>>(src, tgt, out);
    }
}

// Round 5
// 116.709 us; speedup vs baseline: 1.0558x; 1.0053x over previous
//
#include <hip/hip_runtime.h>
#include <hip/hip_bf16.h>

#define BATCH 4
#define CHAN 128
#define HGT 96
#define WID 160
#define HW (HGT * WID)
#define THREADS 512

typedef __attribute__((ext_vector_type(8))) short short8;
typedef __attribute__((ext_vector_type(4))) float float4v;

// Output channel index for displacement (dy,dx), matching _displacements(4) order.
__device__ __forceinline__ int chan_of(int dy, int dx) {
    if (dy == 0 && dx == 0) return 0;
    if (dx == 0) { int i = dy < 0 ? -dy : dy; return 1 + (i - 1) * 20 + (dy < 0 ? 0 : 1); }
    if (dy == 0) { int i = dx < 0 ? -dx : dx; return 1 + (i - 1) * 20 + (dx < 0 ? 2 : 3); }
    int i = dy < 0 ? -dy : dy;
    int j = dx < 0 ? -dx : dx;
    int s = (dy < 0) ? (dx < 0 ? 0 : 2) : (dx < 0 ? 3 : 1);
    return 1 + (i - 1) * 20 + 4 + (j - 1) * 4 + s;
}

// Packed fp32x2 -> bf16x2 (v_cvt_pk_bf16_f32).
__device__ __forceinline__ unsigned pk2(float a, float b) {
    __hip_bfloat162 h = __float22bfloat162_rn(make_float2(a, b));
    unsigned u;
    __builtin_memcpy(&u, &h, 4);
    return u;
}

union sl_u { uint4 v; short8 s; };

// Staging task = (row, oct, xq), xq fastest so 6 consecutive lanes read
// contiguous 16B quads of one channel row (~2 lines per 6 lanes). Each task:
// 8 float4 loads (channels oct*8..+7, 4 pixels each) -> 4 swizzled LDS slots.
// 12 rows * 16 oct * 6 xq = 1152 tasks; u = tid, tid+512, tid+1024 (tid<128).
#define FST_DECODE(TAG, U)                                                    \
    const int u##TAG   = (U);                                                 \
    const int xq##TAG  = u##TAG % 6;                                          \
    const int r6##TAG  = u##TAG / 6;       /* 0..191 */                       \
    const int oct##TAG = r6##TAG & 15;                                        \
    const int row##TAG = r6##TAG >> 4;     /* 0..11 */                        \
    const int gr##TAG  = y0 - 4 + row##TAG;                                   \
    const int gx##TAG  = x0 - 4 + xq##TAG * 4;     /* 16B aligned */          \
    const bool ok##TAG = ((unsigned)gr##TAG < (unsigned)HGT) &&               \
                         ((unsigned)gx##TAG < (unsigned)WID);                 \
    const int ga##TAG  = tb + (oct##TAG * 8 * HGT + gr##TAG) * WID + gx##TAG;

#define FST_ISSUE(TAG, COND)                                                  \
    _Pragma("unroll")                                                         \
    for (int j = 0; j < 8; ++j)                                               \
        p##TAG[j] = (COND) ? *(const float4v*)(tgt + ga##TAG + j * HW)        \
                           : (float4v){0.f, 0.f, 0.f, 0.f};

#define FST_WRITE(TAG)                                                        \
    _Pragma("unroll")                                                         \
    for (int i = 0; i < 4; ++i) {                                             \
        const int xl = xq##TAG * 4 + i;                                       \
        uint4 val;                                                            \
        val.x = pk2(p##TAG[0][i], p##TAG[1][i]);                              \
        val.y = pk2(p##TAG[2][i], p##TAG[3][i]);                              \
        val.z = pk2(p##TAG[4][i], p##TAG[5][i]);                              \
        val.w = pk2(p##TAG[6][i], p##TAG[7][i]);                              \
        s_b[(row##TAG * 24 + xl) * 16 + (oct##TAG ^ (xl & 15))] = val;        \
    }

// One dy-row of the verified MFMA core (DD = static acc index, DYI = dy idx).
#define COMPUTE_DY(DD, DYI)                                                   \
    {                                                                         \
        const int rr = wvy + (DYI);                                           \
        float4v a0 = (float4v){0.f, 0.f, 0.f, 0.f};                           \
        float4v a1 = (float4v){0.f, 0.f, 0.f, 0.f};                           \
        _Pragma("unroll")                                                     \
        for (int ks = 0; ks < 4; ++ks) {                                      \
            sl_u b0;   /* nt=0: x = ln */                                     \
            b0.v = s_b[(rr * 24 + ln) * 16 + ((q + ks * 4) ^ ln)];            \
            a0 = __builtin_amdgcn_mfma_f32_16x16x32_bf16(afr[ks], b0.s, a0, 0, 0, 0); \
        }                                                                     \
        _Pragma("unroll")                                                     \
        for (int ks = 0; ks < 4; ++ks) {                                      \
            sl_u b1;   /* nt=1: x = 16+ln */                                  \
            b1.v = s_b[(rr * 24 + 16 + ln) * 16 + ((q + ks * 4) ^ ln)];       \
            a1 = __builtin_amdgcn_mfma_f32_16x16x32_bf16(afr[ks], b1.s, a1, 0, 0, 0); \
        }                                                                     \
        aa0[DD] = a0; aa1[DD] = a1;                                           \
    }

#define EPI_DY(DD, DYI)                                                       \
    _Pragma("unroll")                                                         \
    for (int reg = 0; reg < 4; ++reg) {                                       \
        const int m = q * 4 + reg;                                            \
        const int t0x = ln - m;             /* dx+4 for nt=0 */               \
        if ((unsigned)t0x <= 8u)                                              \
            s_o[((DYI) * 9 + t0x) * 68 + wvy * 16 + m] = aa0[DD][reg] * inv;  \
        const int t1x = ln + 16 - m;        /* dx+4 for nt=1 */               \
        if ((unsigned)t1x <= 8u)                                              \
            s_o[((DYI) * 9 + t1x) * 68 + wvy * 16 + m] = aa1[DD][reg] * inv;  \
    }

// ---------------------------------------------------------------------------
// Fused single kernel: block = (b, y-quad, x-tile), all 81 displacements.
// 512 threads -> 2 blocks/CU (LDS-limited) = 16 waves/CU for latency hiding.
// Waves 0-3 compute dy 0-3, waves 4-7 compute dy 4-8 (same A per y-sub-row).
// No workspace: tgt staged NCHW f32 -> bf16 in-register (2.25 tasks/thread,
// 3x-amortized vs R1 by the 81-merge). Epilogue = verified LDS-transpose.
// ---------------------------------------------------------------------------
__global__ __launch_bounds__(THREADS, 4)
void cost_volume_fused(const float* __restrict__ src,
                       const float* __restrict__ tgt,
                       float* __restrict__ out) {
    // 12*24*16 = 4608 slots + 128 pad (nt=1 band-masked reads at x up to 31
    // touch them; their products land only in masked-off n-columns).
    __shared__ __align__(16) uint4 s_b[4736];   // 75776 B -> 2 blocks/CU
    __shared__ int s_tab[81];                   // cix -> oc*HW

    const int tid  = threadIdx.x;
    const int wv   = tid >> 6;        // 0..7
    const int wvy  = wv & 3;          // y sub-row
    const int wvd  = wv >> 2;         // 0: dy 0-3, 1: dy 4-8
    const int lane = tid & 63;
    const int q    = lane >> 4;
    const int ln   = lane & 15;

    // XCD-affinity swizzle: blockIdx%8 -> (batch, y-half) slab.
    const int w    = blockIdx.x;      // 0..959
    const int slab = w & 7;
    const int b    = slab >> 1;
    const int yh   = slab & 1;
    const int t    = w >> 3;          // 0..119
    const int x0   = (t % 10) * 16;
    const int y0   = yh * 48 + (t / 10) * 4;

    if (tid < 81) s_tab[tid] = chan_of(tid / 9 - 4, tid % 9 - 4) * HW;

    const int tb = b * CHAN * HGT * WID;

    FST_DECODE(0, tid)
    FST_DECODE(1, tid + 512)
    FST_DECODE(2, tid + 1024)
    const bool has2 = tid < 128;

    float4v p0[8], p1[8], p2[8];

    // ---- in-flight schedule: t0 | A | t1 before first wait ----
    FST_ISSUE(0, ok0)

    const int y = y0 + wvy;
    const int sbase = (b * CHAN * HGT + y) * WID + x0 + ln + q * 8 * HW;
    float apay[32];
    #pragma unroll
    for (int ks = 0; ks < 4; ++ks)
        #pragma unroll
        for (int j = 0; j < 8; ++j)
            apay[ks * 8 + j] = src[sbase + (ks * 32 + j) * HW];

    FST_ISSUE(1, ok1)
    FST_WRITE(0)
    FST_ISSUE(2, has2 && ok2)
    short8 afr[4];
    #pragma unroll
    for (int ks = 0; ks < 4; ++ks) {
        sl_u f;
        f.v.x = pk2(apay[ks * 8 + 0], apay[ks * 8 + 1]);
        f.v.y = pk2(apay[ks * 8 + 2], apay[ks * 8 + 3]);
        f.v.z = pk2(apay[ks * 8 + 4], apay[ks * 8 + 5]);
        f.v.w = pk2(apay[ks * 8 + 6], apay[ks * 8 + 7]);
        afr[ks] = f.s;
    }
    FST_WRITE(1)
    if (has2) { FST_WRITE(2) }

    __syncthreads();

    // ---- compute: this wave's 4 or 5 dys x (8 ds_read_b128 + 8 MFMA) ----
    float4v aa0[5], aa1[5];
    if (wvd == 0) {
        #pragma unroll
        for (int dd = 0; dd < 4; ++dd) COMPUTE_DY(dd, dd)
    } else {
        #pragma unroll
        for (int dd = 0; dd < 5; ++dd) COMPUTE_DY(dd, dd + 4)
    }

    __syncthreads();   // all s_b reads done -> safe to overlay s_o

    // ---- banded accs -> LDS [81 ch][68] f32 ----
    float* s_o = (float*)s_b;
    const float inv = 1.0f / 81.0f;
    if (wvd == 0) {
        #pragma unroll
        for (int dd = 0; dd < 4; ++dd) EPI_DY(dd, dd)
    } else {
        #pragma unroll
        for (int dd = 0; dd < 5; ++dd) EPI_DY(dd, dd + 4)
    }
    __syncthreads();

    // ---- store: 1296 float4 tasks; lanes span x within one (ch,y) row ----
    const size_t ob = (size_t)b * 81 * HW + (size_t)y0 * WID + x0;
    #pragma unroll
    for (int it = 0; it < 3; ++it) {
        const int v = it * THREADS + tid;
        if (v < 1296) {
            const int xq  = v & 3;
            const int row = v >> 2;           // 0..323 = cix*4 + yy
            const int cix = row >> 2;
            const int yy  = row & 3;
            float4v val = *(const float4v*)&s_o[cix * 68 + yy * 16 + xq * 4];
            *(float4v*)&out[ob + s_tab[cix] + yy * WID + xq * 4] = val;
        }
    }
}

extern "C" void kernel_launch(void* const* d_in, const int* in_sizes, int n_in,
                              void* d_out, int out_size, void* d_ws, size_t ws_size,
                              hipStream_t stream) {
    const float* src = (const float*)d_in[0];
    const float* tgt = (const float*)d_in[1];
    float* out = (float*)d_out;
    cost_volume_fused<<<dim3(960, 1, 1), dim3(THREADS, 1, 1), 0, stream>>>(src, tgt, out);
}